// Round 6
// baseline (363.429 us; speedup 1.0000x reference)
//
#include <hip/hip_runtime.h>
#include <math.h>
#include <float.h>

// VideoQuantizer: rmsnorm -> per-subvector argmin over 4096 codewords -> gather -> rmsnorm
// B=8 T=1024 D=1024 Q=8 K=4096 d=128
#define Q_     8
#define K_     4096
#define dd_    128
#define D_     1024
#define ROWS   8192
#define NCHUNK 64
#define TAU    0.02f   // rescue threshold on d2/2 scale: x·δb σ≈2.3e-3 (fp16 B quant) + pack quant 2e-3

typedef _Float16 f16;
typedef __attribute__((ext_vector_type(8))) _Float16 f16x8;
typedef __attribute__((ext_vector_type(4))) float f32x4;
typedef __attribute__((ext_vector_type(4))) unsigned int u32x4;

typedef const __attribute__((address_space(1))) unsigned int* gas_p;
typedef __attribute__((address_space(3))) unsigned int* las_p;

__device__ inline unsigned f2u(float x) { union { float f; unsigned u; } v; v.f = x; return v.u; }
__device__ inline float u2f(unsigned x) { union { unsigned u; float f; } v; v.u = x; return v.f; }
__device__ inline unsigned short f2h(float x) { f16 h = (f16)x; return __builtin_bit_cast(unsigned short, h); }
__device__ inline unsigned umin_(unsigned a, unsigned b) { return a < b ? a : b; }
__device__ inline unsigned umax_(unsigned a, unsigned b) { return a > b ? a : b; }
__device__ inline unsigned long long ullmin_(unsigned long long a, unsigned long long b) { return a < b ? a : b; }

// ---------------- fused: fp16 panel build (negated) + c2/2 | input rmsnorm + x2/2 ----------------
// panels[q][c][n 0..63][slot 0..15][8 fp16] of NEGATED codewords; slot = j ^ (n&15)
__global__ void k_prep(const float* __restrict__ cb, const float* __restrict__ x,
                       const float* __restrict__ w, float* __restrict__ xn,
                       unsigned short* __restrict__ panels, float* __restrict__ c2h,
                       float* __restrict__ x2h, int* __restrict__ counter) {
    const int bid = blockIdx.x, t = threadIdx.x;
    if (bid == 0 && t == 0) *counter = 0;
    if (bid < NCHUNK * Q_) {
        int c = bid & 63, q = bid >> 6;
        const float* src = cb + ((size_t)q * K_ + c * 64) * dd_;
        unsigned short* dst = panels + (size_t)(q * NCHUNK + c) * 8192;   // 16KB per (q,c)
        #pragma unroll
        for (int i = 0; i < 4; i++) {
            int sid = i * 256 + t;
            int n = sid >> 4, j = sid & 15;
            const float* sp = src + n * dd_ + j * 8;
            f32x4 v0 = *(const f32x4*)sp;
            f32x4 v1 = *(const f32x4*)(sp + 4);
            float xs[8] = {v0.x, v0.y, v0.z, v0.w, v1.x, v1.y, v1.z, v1.w};
            unsigned short h[8];
            float ss = 0.0f;
            #pragma unroll
            for (int e = 0; e < 8; e++) {
                float xv = -xs[e];                    // NEGATED codeword
                ss = fmaf(xv, xv, ss);
                h[e] = f2h(xv);                       // RTN fp16
            }
            int slot = j ^ (n & 15);
            u32x4 H;
            H.x = (unsigned)h[0] | ((unsigned)h[1] << 16);
            H.y = (unsigned)h[2] | ((unsigned)h[3] << 16);
            H.z = (unsigned)h[4] | ((unsigned)h[5] << 16);
            H.w = (unsigned)h[6] | ((unsigned)h[7] << 16);
            *(u32x4*)&dst[(n * 16 + slot) * 8] = H;
            ss += __shfl_xor(ss, 1, 64);
            ss += __shfl_xor(ss, 2, 64);
            ss += __shfl_xor(ss, 4, 64);
            ss += __shfl_xor(ss, 8, 64);
            if (j == 0) c2h[q * K_ + c * 64 + n] = 0.5f * ss;
        }
    } else {
        int row = bid - NCHUNK * Q_;
        const float4 v = *(const float4*)(x + (size_t)row * D_ + t * 4);
        float ss = v.x * v.x + v.y * v.y + v.z * v.z + v.w * v.w;
        #pragma unroll
        for (int o = 32; o > 0; o >>= 1) ss += __shfl_xor(ss, o, 64);
        __shared__ float acc[4];
        if ((t & 63) == 0) acc[t >> 6] = ss;
        __syncthreads();
        float tot = (acc[0] + acc[1]) + (acc[2] + acc[3]);
        float sc  = 1.0f / sqrtf(tot * (1.0f / D_) + 1e-5f);
        const float4 wv = *(const float4*)(w + t * 4);
        float4 o;
        o.x = v.x * sc * wv.x; o.y = v.y * sc * wv.y;
        o.z = v.z * sc * wv.z; o.w = v.w * sc * wv.w;
        *(float4*)(xn + (size_t)row * D_ + t * 4) = o;
        float so = o.x * o.x + o.y * o.y + o.z * o.z + o.w * o.w;
        so += __shfl_xor(so, 1, 64);
        so += __shfl_xor(so, 2, 64);
        so += __shfl_xor(so, 4, 64);
        so += __shfl_xor(so, 8, 64);
        so += __shfl_xor(so, 16, 64);
        if ((t & 31) == 0) x2h[row * Q_ + (t >> 5)] = 0.5f * so;
    }
}

// ---------------- fp16 2-pass MFMA distance + packed-u32 top-2 argmin ----------------
// score = x2/2 + c2/2 - x·b_h = d2/2 + x·δb; grid (Q_, ROWS/64): x=q -> per-XCD panel locality.
// Block 64M x 64N, 4 waves 2x2, wave 32M x 32N; dbuf 2x16KB staging.
__launch_bounds__(256, 3)
__global__ void k_dist(const float* __restrict__ xn, const unsigned short* __restrict__ panels,
                       const float* __restrict__ c2h, const float* __restrict__ x2h,
                       int* __restrict__ idxi, float* __restrict__ idxf,
                       int* __restrict__ list, int* __restrict__ counter,
                       unsigned long long* __restrict__ res, int* __restrict__ done) {
    __shared__ char smem[32768];   // 2 x 16KB staging; reduce scratch overlaid after loop

    const int t    = threadIdx.x;
    const int lane = t & 63, wave = t >> 6;
    const int wm = wave >> 1, wn = wave & 1;
    const int col = lane & 15, quad = lane >> 4;
    const int q = blockIdx.x;
    const int row0 = blockIdx.y * 64;

    // A fragments: fp16 trunc-split hi+lo, 2 m-tiles x 4 k-steps
    f16x8 ah[2][4], al[2][4];
    #pragma unroll
    for (int mt = 0; mt < 2; mt++) {
        #pragma unroll
        for (int kt = 0; kt < 4; kt++) {
            const float* ap = xn + (size_t)(row0 + wm * 32 + mt * 16 + col) * D_
                              + q * dd_ + kt * 32 + quad * 8;
            f32x4 v0 = *(const f32x4*)ap;
            f32x4 v1 = *(const f32x4*)(ap + 4);
            #pragma unroll
            for (int e = 0; e < 8; e++) {
                float xv = (e < 4) ? v0[e] : v1[e - 4];
                f16 hh = (f16)xv;
                ah[mt][kt][e] = hh;
                al[mt][kt][e] = (f16)(xv - (float)hh);
            }
        }
    }

    // per-slot row halves of ||x_q||^2
    f32x4 x2v[2];
    #pragma unroll
    for (int mt = 0; mt < 2; mt++)
        #pragma unroll
        for (int r = 0; r < 4; r++)
            x2v[mt][r] = x2h[(size_t)(row0 + wm * 32 + mt * 16 + quad * 4 + r) * Q_ + q];

    unsigned m1[8], m2[8];
    #pragma unroll
    for (int i = 0; i < 8; i++) { m1[i] = 0xFFFFFFFFu; m2[i] = 0xFFFFFFFFu; }

    const size_t panq = (size_t)q * NCHUNK * 8192;
    const float* c2hq = c2h + q * K_;

    // preload chunk 0
    {
        const unsigned short* src = panels + panq;
        #pragma unroll
        for (int i = 0; i < 4; i++) {
            int boff = i * 4096 + t * 16;
            __builtin_amdgcn_global_load_lds((gas_p)((const char*)src + boff),
                                             (las_p)(smem + boff), 16, 0, 0);
        }
    }
    float ch0 = c2hq[wn * 32 + col];
    float ch1 = c2hq[wn * 32 + col + 16];

    for (int c = 0; c < NCHUNK; c++) {
        __syncthreads();
        if (c + 1 < NCHUNK) {
            const unsigned short* src = panels + panq + (size_t)(c + 1) * 8192;
            char* stage = smem + ((c + 1) & 1) * 16384;
            #pragma unroll
            for (int i = 0; i < 4; i++) {
                int boff = i * 4096 + t * 16;
                __builtin_amdgcn_global_load_lds((gas_p)((const char*)src + boff),
                                                 (las_p)(stage + boff), 16, 0, 0);
            }
        }
        float ch0n = 0.0f, ch1n = 0.0f;
        if (c + 1 < NCHUNK) {
            ch0n = c2hq[(c + 1) * 64 + wn * 32 + col];
            ch1n = c2hq[(c + 1) * 64 + wn * 32 + col + 16];
        }
        const char* cbuf = smem + (c & 1) * 16384;

        f32x4 acc[2][2];
        #pragma unroll
        for (int mt = 0; mt < 2; mt++) {
            acc[mt][0] = x2v[mt] + ch0;   // d2/2 accumulator init
            acc[mt][1] = x2v[mt] + ch1;
        }

        #pragma unroll
        for (int kt = 0; kt < 4; kt++) {
            const int sw = ((kt * 4 + quad) ^ col) * 16;
            const int a0 = (wn * 32 + col) * 256 + sw;
            const int a1 = (wn * 32 + 16 + col) * 256 + sw;
            f16x8 b0 = *(const f16x8*)(cbuf + a0);
            f16x8 b1 = *(const f16x8*)(cbuf + a1);
            #pragma unroll
            for (int mt = 0; mt < 2; mt++) {
                acc[mt][0] = __builtin_amdgcn_mfma_f32_16x16x32_f16(ah[mt][kt], b0, acc[mt][0], 0, 0, 0);
                acc[mt][1] = __builtin_amdgcn_mfma_f32_16x16x32_f16(ah[mt][kt], b1, acc[mt][1], 0, 0, 0);
                acc[mt][0] = __builtin_amdgcn_mfma_f32_16x16x32_f16(al[mt][kt], b0, acc[mt][0], 0, 0, 0);
                acc[mt][1] = __builtin_amdgcn_mfma_f32_16x16x32_f16(al[mt][kt], b1, acc[mt][1], 0, 0, 0);
            }
        }

        const unsigned tg0 = (unsigned)(c << 1), tg1 = tg0 | 1u;
        #pragma unroll
        for (int mt = 0; mt < 2; mt++) {
            #pragma unroll
            for (int r = 0; r < 4; r++) {
                const int sl = mt * 4 + r;
                unsigned p0 = (f2u(acc[mt][0][r]) & 0xFFFFFF80u) | tg0;
                m2[sl] = umin_(m2[sl], umax_(m1[sl], p0));
                m1[sl] = umin_(m1[sl], p0);
                unsigned p1 = (f2u(acc[mt][1][r]) & 0xFFFFFF80u) | tg1;
                m2[sl] = umin_(m2[sl], umax_(m1[sl], p1));
                m1[sl] = umin_(m1[sl], p1);
            }
        }
        ch0 = ch0n; ch1 = ch1n;
    }

    // cross-lane top-2 merge per row (u32 domain; stride 33)
    __syncthreads();
    unsigned* rm1 = (unsigned*)smem;             // [64][33]
    unsigned* rm2 = (unsigned*)(smem + 8448);
    #pragma unroll
    for (int mt = 0; mt < 2; mt++) {
        #pragma unroll
        for (int r = 0; r < 4; r++) {
            int sl = mt * 4 + r;
            int row_l = wm * 32 + mt * 16 + quad * 4 + r;
            int e = wn * 16 + col;
            rm1[row_l * 33 + e] = m1[sl];
            rm2[row_l * 33 + e] = m2[sl];
        }
    }
    __syncthreads();
    if (t < 64) {
        unsigned b1 = 0xFFFFFFFFu, b2 = 0xFFFFFFFFu;
        int be = 0;
        for (int e = 0; e < 32; e++) {
            unsigned v1 = rm1[t * 33 + e], v2 = rm2[t * 33 + e];
            b2 = umin_(b2, v2);
            if (v1 < b1) { b2 = umin_(b2, b1); b1 = v1; be = e; }
            else         { b2 = umin_(b2, v1); }
        }
        int tag = (int)(b1 & 0x7Fu);
        int k = ((tag >> 1) << 6) | ((be >> 4) << 5) | ((tag & 1) << 4) | (be & 15);
        float f1 = u2f(b1 & 0xFFFFFF80u);
        float f2 = u2f(b2 & 0xFFFFFF80u);
        int rg = row0 + t;
        idxi[rg * Q_ + q] = k;
        idxf[rg * Q_ + q] = (float)k;
        if (f2 - f1 < TAU) {                 // quantized ties -> gap 0 -> always rescued
            int p = atomicAdd(counter, 1);
            list[p] = rg * Q_ + q;
            res[p]  = ~0ull;
            done[p] = 0;
        }
    }
}

// ---------------- exact fp32 re-score, sliced: 4 blocks x 1024 codewords per flagged item ----
// Partial mins merged via u64 atomicMin (order-flipped float score << 32 | k -> exact first-min).
__global__ void k_rescue(const float* __restrict__ xn, const float* __restrict__ cb,
                         const float* __restrict__ c2h, const int* __restrict__ list,
                         const int* __restrict__ counter, unsigned long long* __restrict__ res,
                         int* __restrict__ done, int* __restrict__ idxi, float* __restrict__ idxf) {
    __shared__ float xq[dd_];
    __shared__ unsigned long long red[256];
    const int n = *counter;
    const int t = threadIdx.x;
    for (int u = blockIdx.x; u < n * 4; u += gridDim.x) {
        int it = u >> 2, slice = u & 3;
        int item = list[it];
        int rg = item >> 3, q = item & 7;
        __syncthreads();
        if (t < dd_) xq[t] = xn[(size_t)rg * D_ + q * dd_ + t];
        __syncthreads();
        unsigned long long best = ~0ull;
        for (int i = 0; i < 4; i++) {
            int k = slice * 1024 + i * 256 + t;
            const float* cp = cb + ((size_t)q * K_ + k) * dd_;
            float dot = 0.0f;
            #pragma unroll 8
            for (int d = 0; d < dd_; d += 4) {
                f32x4 cv = *(const f32x4*)(cp + d);
                dot = fmaf(cv.x, xq[d],     dot);
                dot = fmaf(cv.y, xq[d + 1], dot);
                dot = fmaf(cv.z, xq[d + 2], dot);
                dot = fmaf(cv.w, xq[d + 3], dot);
            }
            float s = c2h[q * K_ + k] - dot;       // d2/2 - x2/2 (monotone in d2, can be <0)
            unsigned su = f2u(s);
            su = (su & 0x80000000u) ? ~su : (su | 0x80000000u);   // order-preserving flip
            best = ullmin_(best, ((unsigned long long)su << 32) | (unsigned)k);
        }
        red[t] = best;
        __syncthreads();
        #pragma unroll
        for (int off = 128; off > 0; off >>= 1) {
            if (t < off) red[t] = ullmin_(red[t], red[t + off]);
            __syncthreads();
        }
        if (t == 0) {
            atomicMin(&res[it], red[0]);
            __threadfence();
            if (atomicAdd(&done[it], 1) == 3) {    // last slice applies
                unsigned long long r = atomicAdd(&res[it], 0ull);
                int k = (int)(r & 0xFFFFFFFFull);
                idxi[item] = k;
                idxf[item] = (float)k;
            }
        }
    }
}

// ---------------- gather + output rmsnorm ----------------
__global__ void k_out(const float* __restrict__ cb, const int* __restrict__ idx_i,
                      const float* __restrict__ w, float* __restrict__ out) {
    int row = blockIdx.x;
    int t   = threadIdx.x;
    __shared__ int   sidx[Q_];
    __shared__ float acc[4];
    if (t < Q_) sidx[t] = idx_i[row * Q_ + t];
    __syncthreads();
    int col = t * 4;
    int q   = col >> 7;
    int dc  = col & 127;
    const float4 v = *(const float4*)(cb + ((size_t)q * K_ + sidx[q]) * dd_ + dc);
    float ss = v.x * v.x + v.y * v.y + v.z * v.z + v.w * v.w;
    #pragma unroll
    for (int o = 32; o > 0; o >>= 1) ss += __shfl_xor(ss, o, 64);
    if ((t & 63) == 0) acc[t >> 6] = ss;
    __syncthreads();
    float tot = (acc[0] + acc[1]) + (acc[2] + acc[3]);
    float sc  = 1.0f / sqrtf(tot * (1.0f / D_) + 1e-5f);
    const float4 wv = *(const float4*)(w + col);
    float4 o;
    o.x = v.x * sc * wv.x; o.y = v.y * sc * wv.y;
    o.z = v.z * sc * wv.z; o.w = v.w * sc * wv.w;
    *(float4*)(out + (size_t)row * D_ + col) = o;
}

extern "C" void kernel_launch(void* const* d_in, const int* in_sizes, int n_in,
                              void* d_out, int out_size, void* d_ws, size_t ws_size,
                              hipStream_t stream) {
    const float* x     = (const float*)d_in[0];
    const float* cb    = (const float*)d_in[1];
    const float* w_in  = (const float*)d_in[2];
    const float* w_out = (const float*)d_in[3];

    float* out  = (float*)d_out;                  // xn lives here between k_prep and k_out
    float* idxf = out + (size_t)ROWS * D_;

    // ws: panels 8MB | c2h 128KB | x2h 256KB | idxi 256KB | list 256KB | done 256KB | counter | res 512KB
    unsigned short* panels = (unsigned short*)d_ws;
    float* c2h  = (float*)((char*)d_ws + (8u << 20));
    float* x2h  = c2h + Q_ * K_;
    int*   idxi = (int*)(x2h + (size_t)ROWS * Q_);
    int*   list = idxi + ROWS * Q_;
    int*   done = list + ROWS * Q_;
    int*   counter = done + ROWS * Q_;
    unsigned long long* res = (unsigned long long*)(counter + 64);

    k_prep  <<<dim3(NCHUNK * Q_ + ROWS), 256, 0, stream>>>(cb, x, w_in, out, panels, c2h, x2h, counter);
    k_dist  <<<dim3(Q_, ROWS / 64),      256, 0, stream>>>(out, panels, c2h, x2h, idxi, idxf,
                                                           list, counter, res, done);
    k_rescue<<<dim3(2048),               256, 0, stream>>>(out, cb, c2h, list, counter, res, done, idxi, idxf);
    k_out   <<<dim3(ROWS),               256, 0, stream>>>(cb, idxi, w_out, out);
}